// Round 1
// baseline (26092.102 us; speedup 1.0000x reference)
//
#include <hip/hip_runtime.h>
#include <hip/hip_bf16.h>
#include <math.h>

// Problem dims
#define NB   128
#define NP   196
#define DENC 2048
#define DDEC 512
#define DATT 512
#define DEMB 512
#define NV   10000
#define NT   30
#define NTM  29   // NT-1

__device__ __forceinline__ float sigmoidf_(float x) { return 1.f / (1.f + __expf(-x)); }

// ---------------------------------------------------------------------------
// Sort: stable descending argsort of lens (B=128), writes caps/len_dec/order
// outputs (as float) and int copies to ws.
// ---------------------------------------------------------------------------
__global__ void sort_kernel(const int* __restrict__ len_caps,
                            const int* __restrict__ enc_caps,
                            float* __restrict__ out_caps,
                            float* __restrict__ out_lendec,
                            float* __restrict__ out_order,
                            int* __restrict__ order_ws,
                            int* __restrict__ lendec_ws,
                            int* __restrict__ caps_ws) {
    __shared__ int lens[NB];
    int i = threadIdx.x;
    lens[i] = len_caps[i];   // len_caps is (B,1)
    __syncthreads();
    int li = lens[i];
    int r = 0;
    for (int j = 0; j < NB; ++j) {
        int lj = lens[j];
        if (lj > li || (lj == li && j < i)) r++;
    }
    order_ws[r]   = i;
    out_order[r]  = (float)i;
    int ld        = li - 1;
    lendec_ws[r]  = ld;
    out_lendec[r] = (float)ld;
    for (int k = 0; k < NT; ++k) {
        int cv = enc_caps[i * NT + k];
        caps_ws[r * NT + k]  = cv;
        out_caps[r * NT + k] = (float)cv;
    }
}

// rowmap[m] = order[m/196]*196 + m%196, m in [0, 25088)
__global__ void rowmap_kernel(const int* __restrict__ order, int* __restrict__ rowmap) {
    int m = blockIdx.x * 256 + threadIdx.x;
    rowmap[m] = order[m / NP] * NP + (m % NP);
}

// embeds[b][t][d] = emb[caps_sorted[b][t]][d], t<29
__global__ void embed_kernel(const float* __restrict__ emb,
                             const int* __restrict__ caps,
                             float* __restrict__ embeds) {
    int idx = blockIdx.x * 256 + threadIdx.x;   // < 128*29*512
    int d  = idx & 511;
    int bt = idx >> 9;
    int b  = bt / NTM, tt = bt % NTM;
    embeds[idx] = emb[(long)caps[b * NT + tt] * DEMB + d];
}

// mu[b][d] = mean_p enc[order[b]][p][d]
__global__ void mu_kernel(const float* __restrict__ enc,
                          const int* __restrict__ order,
                          float* __restrict__ mu) {
    int b = blockIdx.x;
    int d = blockIdx.y * 256 + threadIdx.x;
    const float* eb = enc + (long)order[b] * NP * DENC;
    float s = 0.f;
    for (int p = 0; p < NP; ++p) s += eb[(long)p * DENC + d];
    mu[(long)b * DENC + d] = s * (1.f / (float)NP);
}

// ---------------------------------------------------------------------------
// Generic fp32 GEMM: C[m][n] = act( A[m][:] . W[n][:] + bias[n] (+ C) ) * mask
// A: M x K (lda), optional rowmap for physical A row; W: N x K (ldw).
// 64x64 tile, K-tile 16, 256 threads, 4x4 microtile. LDS stride 65 -> no
// bank conflicts on load or compute paths.
// ---------------------------------------------------------------------------
__global__ __launch_bounds__(256) void gemm_k(
    const float* __restrict__ A, long lda, const int* __restrict__ rowmap,
    const float* __restrict__ W, long ldw,
    const float* __restrict__ bias,
    float* __restrict__ C, long ldc,
    int M, int N, int K,
    int accumulate, int act,
    const int* __restrict__ mask_len, int t) {
    __shared__ float As[16][65];
    __shared__ float Ws[16][65];
    const int m0 = blockIdx.y * 64, n0 = blockIdx.x * 64;
    const int tid = threadIdx.x;
    const int ti = tid & 15, tj = tid >> 4;
    float acc[4][4] = {};
    const int lk = ti, lm = tj;
    for (int k0 = 0; k0 < K; k0 += 16) {
#pragma unroll
        for (int l = 0; l < 4; ++l) {
            int m  = lm + 16 * l;
            int gm = m0 + m;
            int row = rowmap ? rowmap[gm] : gm;
            As[lk][m] = A[(long)row * lda + k0 + lk];
        }
#pragma unroll
        for (int l = 0; l < 4; ++l) {
            int n  = lm + 16 * l;
            int gn = n0 + n;
            Ws[lk][n] = (gn < N) ? W[(long)gn * ldw + k0 + lk] : 0.f;
        }
        __syncthreads();
#pragma unroll
        for (int kk = 0; kk < 16; ++kk) {
            float a[4], w[4];
#pragma unroll
            for (int i = 0; i < 4; ++i) a[i] = As[kk][ti + 16 * i];
#pragma unroll
            for (int j = 0; j < 4; ++j) w[j] = Ws[kk][tj + 16 * j];
#pragma unroll
            for (int i = 0; i < 4; ++i)
#pragma unroll
                for (int j = 0; j < 4; ++j) acc[i][j] = fmaf(a[i], w[j], acc[i][j]);
        }
        __syncthreads();
    }
#pragma unroll
    for (int i = 0; i < 4; ++i) {
        int gm = m0 + ti + 16 * i;
        float msk = 1.f;
        if (mask_len) msk = (t < mask_len[gm]) ? 1.f : 0.f;
#pragma unroll
        for (int j = 0; j < 4; ++j) {
            int gn = n0 + tj + 16 * j;
            if (gn < N) {
                float v = acc[i][j];
                if (bias) v += bias[gn];
                if (accumulate) v += C[(long)gm * ldc + gn];
                if (act == 1) v = sigmoidf_(v);
                C[(long)gm * ldc + gn] = v * msk;
            }
        }
    }
}

// ---------------------------------------------------------------------------
// e[b][p] = sum_d relu(att_enc[b][p][d] + att_dec[b][d]) * W_att[d] + b_att
// One wave per (b,p) row; 4 waves / block.
// ---------------------------------------------------------------------------
__global__ void att_e_kernel(const float* __restrict__ att_enc,
                             const float* __restrict__ att_dec,
                             const float* __restrict__ W_att,
                             const float* __restrict__ b_att,
                             float* __restrict__ e) {
    int wid  = threadIdx.x >> 6;
    int lane = threadIdx.x & 63;
    int row  = blockIdx.x * 4 + wid;  // < 25088
    int b    = row / NP;
    const float* ae = att_enc + (long)row * DATT;
    const float* ad = att_dec + (long)b * DATT;
    float s = 0.f;
#pragma unroll
    for (int i = 0; i < DATT / 64; ++i) {
        int d = lane + 64 * i;
        float v = ae[d] + ad[d];
        v = v > 0.f ? v : 0.f;
        s += v * W_att[d];
    }
#pragma unroll
    for (int o = 32; o; o >>= 1) s += __shfl_down(s, o, 64);
    if (lane == 0) e[row] = s + b_att[0];
}

// softmax over p=196 per b; writes alpha (unmasked, ws) and alpha*m to out.
__global__ void softmax_kernel(const float* __restrict__ e,
                               float* __restrict__ alpha,
                               float* __restrict__ out_alpha,
                               const int* __restrict__ lendec, int t) {
    int b = blockIdx.x, lane = threadIdx.x;  // 64 threads
    const float* eb = e + (long)b * NP;
    float v[4];
    float mx = -1e30f;
#pragma unroll
    for (int i = 0; i < 4; ++i) {
        int p = lane + 64 * i;
        v[i]  = (p < NP) ? eb[p] : -1e30f;
        mx    = fmaxf(mx, v[i]);
    }
#pragma unroll
    for (int o = 32; o; o >>= 1) mx = fmaxf(mx, __shfl_xor(mx, o, 64));
    float s = 0.f;
#pragma unroll
    for (int i = 0; i < 4; ++i) {
        int p = lane + 64 * i;
        v[i]  = (p < NP) ? __expf(v[i] - mx) : 0.f;
        s += v[i];
    }
#pragma unroll
    for (int o = 32; o; o >>= 1) s += __shfl_xor(s, o, 64);
    float inv = 1.f / s;
    float m   = (t < lendec[b]) ? 1.f : 0.f;
#pragma unroll
    for (int i = 0; i < 4; ++i) {
        int p = lane + 64 * i;
        if (p < NP) {
            float a = v[i] * inv;
            alpha[(long)b * NP + p] = a;
            out_alpha[((long)b * NTM + t) * NP + p] = a * m;
        }
    }
}

// weighted[b][d] = sum_p alpha[b][p] * enc[order[b]][p][d]
__global__ void weighted_kernel(const float* __restrict__ enc,
                                const float* __restrict__ alpha,
                                const int* __restrict__ order,
                                float* __restrict__ weighted) {
    int b = blockIdx.x;
    int d = blockIdx.y * 256 + threadIdx.x;
    __shared__ float al[NP];
    if (threadIdx.x < NP) al[threadIdx.x] = alpha[(long)b * NP + threadIdx.x];
    __syncthreads();
    const float* eb = enc + (long)order[b] * NP * DENC;
    float s = 0.f;
    for (int p = 0; p < NP; ++p) s += al[p] * eb[(long)p * DENC + d];
    weighted[(long)b * DENC + d] = s;
}

// x = concat(emb_t, weighted*gate): 128 x 2560
__global__ void build_x_kernel(const float* __restrict__ embeds,
                               const float* __restrict__ weighted,
                               const float* __restrict__ gate,
                               float* __restrict__ x, int t) {
    int idx = blockIdx.x * 256 + threadIdx.x;  // < 128*2560
    int b = idx / 2560, col = idx % 2560;
    float v;
    if (col < DEMB) {
        v = embeds[((long)b * NTM + t) * DEMB + col];
    } else {
        int d = col - DEMB;
        v = weighted[(long)b * DENC + d] * gate[(long)b * DENC + d];
    }
    x[idx] = v;
}

// LSTM pointwise: c_new/h_new, masked carry update in place, hnew saved.
__global__ void lstm_kernel(const float* __restrict__ gates,
                            float* __restrict__ c,
                            float* __restrict__ h,
                            float* __restrict__ hnew,
                            const int* __restrict__ lendec, int t) {
    int idx = blockIdx.x * 256 + threadIdx.x;  // < 128*512
    int b = idx >> 9, d = idx & 511;
    const float* g = gates + ((long)b << 11);
    float ig = sigmoidf_(g[d]);
    float fg = sigmoidf_(g[512 + d]);
    float gg = tanhf(g[1024 + d]);
    float og = sigmoidf_(g[1536 + d]);
    float cn = fg * c[idx] + ig * gg;
    float hn = og * tanhf(cn);
    hnew[idx] = hn;
    if (t < lendec[b]) {
        h[idx] = hn;
        c[idx] = cn;
    }
}

// ---------------------------------------------------------------------------
extern "C" void kernel_launch(void* const* d_in, const int* in_sizes, int n_in,
                              void* d_out, int out_size, void* d_ws, size_t ws_size,
                              hipStream_t stream) {
    const float* enc_out   = (const float*)d_in[0];
    const int*   enc_caps  = (const int*)d_in[1];
    const int*   len_caps  = (const int*)d_in[2];
    const float* emb       = (const float*)d_in[3];
    const float* W_enc_att = (const float*)d_in[4];
    const float* b_enc_att = (const float*)d_in[5];
    const float* W_dec_att = (const float*)d_in[6];
    const float* b_dec_att = (const float*)d_in[7];
    const float* W_att     = (const float*)d_in[8];
    const float* b_att     = (const float*)d_in[9];
    const float* W_init_h  = (const float*)d_in[10];
    const float* b_init_h  = (const float*)d_in[11];
    const float* W_init_c  = (const float*)d_in[12];
    const float* b_init_c  = (const float*)d_in[13];
    const float* W_ih      = (const float*)d_in[14];
    const float* b_ih      = (const float*)d_in[15];
    const float* W_hh      = (const float*)d_in[16];
    const float* b_hh      = (const float*)d_in[17];
    const float* W_fbeta   = (const float*)d_in[18];
    const float* b_fbeta   = (const float*)d_in[19];
    const float* W_fc      = (const float*)d_in[20];
    const float* b_fc      = (const float*)d_in[21];

    // Output layout (flat, return order): caps, len_dec, predictions, alphas, order
    float* out        = (float*)d_out;
    float* out_caps   = out;                               // 128*30
    float* out_lendec = out + 3840;                        // 128
    float* out_pred   = out + 3968;                        // 128*29*10000
    float* out_alpha  = out + 3968 + 37120000;             // 128*29*196
    float* out_order  = out + 3968 + 37120000 + 727552;    // 128

    // Workspace carve
    char*  wsb = (char*)d_ws;
    size_t off = 0;
    auto alloc = [&](size_t bytes) -> void* {
        void* p = wsb + off;
        off += (bytes + 255) & ~(size_t)255;
        return p;
    };
    int*   order_ws  = (int*)alloc(NB * 4);
    int*   lendec_ws = (int*)alloc(NB * 4);
    int*   caps_ws   = (int*)alloc(NB * NT * 4);
    int*   rowmap    = (int*)alloc((size_t)NB * NP * 4);
    float* embeds    = (float*)alloc((size_t)NB * NTM * DEMB * 4);
    float* mu        = (float*)alloc((size_t)NB * DENC * 4);
    float* h         = (float*)alloc((size_t)NB * DDEC * 4);
    float* c         = (float*)alloc((size_t)NB * DDEC * 4);
    float* hnew      = (float*)alloc((size_t)NB * DDEC * 4);
    float* att_enc   = (float*)alloc((size_t)NB * NP * DATT * 4);
    float* att_dec   = (float*)alloc((size_t)NB * DATT * 4);
    float* e_ws      = (float*)alloc((size_t)NB * NP * 4);
    float* alpha_ws  = (float*)alloc((size_t)NB * NP * 4);
    float* weighted  = (float*)alloc((size_t)NB * DENC * 4);
    float* gate      = (float*)alloc((size_t)NB * DENC * 4);
    float* xbuf      = (float*)alloc((size_t)NB * (DEMB + DENC) * 4);
    float* gates     = (float*)alloc((size_t)NB * 4 * DDEC * 4);

    // Prologue
    sort_kernel<<<1, NB, 0, stream>>>(len_caps, enc_caps, out_caps, out_lendec,
                                      out_order, order_ws, lendec_ws, caps_ws);
    rowmap_kernel<<<98, 256, 0, stream>>>(order_ws, rowmap);            // 25088
    embed_kernel<<<7424, 256, 0, stream>>>(emb, caps_ws, embeds);       // 128*29*512
    mu_kernel<<<dim3(NB, DENC / 256), 256, 0, stream>>>(enc_out, order_ws, mu);

    // h = mu @ W_init_h^T + b; c likewise  (M=128,N=512,K=2048)
    gemm_k<<<dim3(DDEC / 64, NB / 64), 256, 0, stream>>>(
        mu, DENC, nullptr, W_init_h, DENC, b_init_h, h, DDEC,
        NB, DDEC, DENC, 0, 0, nullptr, 0);
    gemm_k<<<dim3(DDEC / 64, NB / 64), 256, 0, stream>>>(
        mu, DENC, nullptr, W_init_c, DENC, b_init_c, c, DDEC,
        NB, DDEC, DENC, 0, 0, nullptr, 0);

    // att_enc = enc_sorted @ W_enc_att^T + b  (M=25088,N=512,K=2048)
    gemm_k<<<dim3(DATT / 64, (NB * NP) / 64), 256, 0, stream>>>(
        enc_out, DENC, rowmap, W_enc_att, DENC, b_enc_att, att_enc, DATT,
        NB * NP, DATT, DENC, 0, 0, nullptr, 0);

    for (int t = 0; t < NTM; ++t) {
        // att_dec = h @ W_dec_att^T + b  (128x512x512)
        gemm_k<<<dim3(DATT / 64, NB / 64), 256, 0, stream>>>(
            h, DDEC, nullptr, W_dec_att, DDEC, b_dec_att, att_dec, DATT,
            NB, DATT, DDEC, 0, 0, nullptr, 0);
        // e scores
        att_e_kernel<<<(NB * NP) / 4, 256, 0, stream>>>(att_enc, att_dec, W_att,
                                                        b_att, e_ws);
        // softmax + masked alpha output
        softmax_kernel<<<NB, 64, 0, stream>>>(e_ws, alpha_ws, out_alpha, lendec_ws, t);
        // weighted context
        weighted_kernel<<<dim3(NB, DENC / 256), 256, 0, stream>>>(enc_out, alpha_ws,
                                                                  order_ws, weighted);
        // gate = sigmoid(h @ W_fbeta^T + b)  (128x2048x512)
        gemm_k<<<dim3(DENC / 64, NB / 64), 256, 0, stream>>>(
            h, DDEC, nullptr, W_fbeta, DDEC, b_fbeta, gate, DENC,
            NB, DENC, DDEC, 0, 1, nullptr, 0);
        // x = [emb_t, weighted*gate]
        build_x_kernel<<<(NB * (DEMB + DENC)) / 256, 256, 0, stream>>>(
            embeds, weighted, gate, xbuf, t);
        // gates = x @ W_ih^T + b_ih  (128x2048x2560)
        gemm_k<<<dim3((4 * DDEC) / 64, NB / 64), 256, 0, stream>>>(
            xbuf, DEMB + DENC, nullptr, W_ih, DEMB + DENC, b_ih, gates, 4 * DDEC,
            NB, 4 * DDEC, DEMB + DENC, 0, 0, nullptr, 0);
        // gates += h @ W_hh^T + b_hh  (128x2048x512)
        gemm_k<<<dim3((4 * DDEC) / 64, NB / 64), 256, 0, stream>>>(
            h, DDEC, nullptr, W_hh, DDEC, b_hh, gates, 4 * DDEC,
            NB, 4 * DDEC, DDEC, 1, 0, nullptr, 0);
        // LSTM pointwise + masked carry update
        lstm_kernel<<<(NB * DDEC) / 256, 256, 0, stream>>>(gates, c, h, hnew,
                                                           lendec_ws, t);
        // preds = hnew @ W_fc^T + b_fc, masked, written straight to output
        gemm_k<<<dim3((NV + 63) / 64, NB / 64), 256, 0, stream>>>(
            hnew, DDEC, nullptr, W_fc, DDEC, b_fc, out_pred + (long)t * NV,
            (long)NTM * NV, NB, NV, DDEC, 0, 0, lendec_ws, t);
    }
}

// Round 2
// 5612.054 us; speedup vs baseline: 4.6493x; 4.6493x over previous
//
#include <hip/hip_runtime.h>
#include <hip/hip_bf16.h>
#include <math.h>

#define NB   128
#define NP   196
#define DENC 2048
#define DDEC 512
#define NV   10000
#define NT   30
#define NTM  29

typedef __attribute__((ext_vector_type(8))) short short8;
typedef __attribute__((ext_vector_type(4))) float f32x4;

__device__ __forceinline__ float sigmoidf_(float x) { return 1.f / (1.f + __expf(-x)); }
__device__ __forceinline__ unsigned short f2bf(float x) {
    unsigned int u = __float_as_uint(x);
    u += 0x7fffu + ((u >> 16) & 1u);   // RNE
    return (unsigned short)(u >> 16);
}
__device__ __forceinline__ float bf2f(unsigned short h) {
    return __uint_as_float(((unsigned int)h) << 16);
}

// ---------------------------------------------------------------------------
// Sort + nt[t] (active prefix length per step)
// ---------------------------------------------------------------------------
__global__ void sort_kernel(const int* __restrict__ len_caps,
                            const int* __restrict__ enc_caps,
                            float* __restrict__ out_caps,
                            float* __restrict__ out_lendec,
                            float* __restrict__ out_order,
                            int* __restrict__ order_ws,
                            int* __restrict__ nt_ws,
                            int* __restrict__ caps_ws) {
    __shared__ int lens[NB];
    int i = threadIdx.x;
    lens[i] = len_caps[i];
    __syncthreads();
    int li = lens[i];
    int r = 0;
    for (int j = 0; j < NB; ++j) {
        int lj = lens[j];
        if (lj > li || (lj == li && j < i)) r++;
    }
    order_ws[r]   = i;
    out_order[r]  = (float)i;
    out_lendec[r] = (float)(li - 1);
    for (int k = 0; k < NT; ++k) {
        int cv = enc_caps[i * NT + k];
        caps_ws[r * NT + k]  = cv;
        out_caps[r * NT + k] = (float)cv;
    }
    if (i < NTM) {
        int cnt = 0;
        for (int j = 0; j < NB; ++j) cnt += (lens[j] - 1 > i) ? 1 : 0;
        nt_ws[i] = cnt;
    }
}

__global__ void rowmap_kernel(const int* __restrict__ order, int* __restrict__ rowmap) {
    int m = blockIdx.x * 256 + threadIdx.x;
    rowmap[m] = order[m / NP] * NP + (m % NP);
}

__global__ void mu_kernel(const float* __restrict__ enc,
                          const int* __restrict__ order,
                          float* __restrict__ mu) {
    int b = blockIdx.x;
    int d = blockIdx.y * 256 + threadIdx.x;
    const float* eb = enc + (long)order[b] * NP * DENC;
    float s = 0.f;
    for (int p = 0; p < NP; ++p) s += eb[(long)p * DENC + d];
    mu[(long)b * DENC + d] = s * (1.f / (float)NP);
}

__global__ void fill_zero4(float4* __restrict__ p, int n4) {
    int i = blockIdx.x * 256 + threadIdx.x;
    if (i < n4) p[i] = make_float4(0.f, 0.f, 0.f, 0.f);
}

__global__ void conv_bf(const float* __restrict__ s, unsigned short* __restrict__ d, int n) {
    int i = blockIdx.x * 256 + threadIdx.x;
    if (i < n) d[i] = f2bf(s[i]);
}

// W_ihh[n][k] = k<2560 ? W_ih[n][k] : W_hh[n][k-2560]; grid (12, 2048)
__global__ void kconcat_ihh(const float* __restrict__ W_ih, const float* __restrict__ W_hh,
                            unsigned short* __restrict__ dst) {
    int n = blockIdx.y;
    int k = blockIdx.x * 256 + threadIdx.x;   // < 3072
    float v = (k < 2560) ? W_ih[(long)n * 2560 + k] : W_hh[(long)n * 512 + (k - 2560)];
    dst[(long)n * 3072 + k] = f2bf(v);
}

__global__ void bias_add2(const float* __restrict__ a, const float* __restrict__ b,
                          float* __restrict__ d, int n) {
    int i = blockIdx.x * 256 + threadIdx.x;
    if (i < n) d[i] = a[i] + b[i];
}

// ---------------------------------------------------------------------------
// bf16 MFMA GEMM: out[m][n] = act(A[m][:].W[n][:] + bias[n])
// BM=64 BN=128 BK=32; 256 thr = 4 waves (2x2), wave tile 32x64 (2x4 frags of
// 16x16x32). A fp32 (converted in staging), W bf16 (N x K row-major).
// Two output segments split at column `split` (separate ptr/bias/act), or
// bf16 output via outbf. Row limit nt[t] (active-prefix pruning).
// ---------------------------------------------------------------------------
__global__ __launch_bounds__(256) void gemm_mfma(
    const float* __restrict__ A, long lda, const int* __restrict__ rowmap,
    const unsigned short* __restrict__ W, long ldw,
    const float* __restrict__ bias0, const float* __restrict__ bias1, int split,
    float* __restrict__ out0, long ld0, float* __restrict__ out1, long ld1,
    unsigned short* __restrict__ outbf,
    int act0, int act1, int M, int N, int K,
    const int* __restrict__ nt, int t) {
    __shared__ __align__(16) unsigned short As[64 * 32];
    __shared__ __align__(16) unsigned short Bs[128 * 32];
    const int limit = nt ? nt[t] : M;
    const int m0 = blockIdx.y * 64;
    if (m0 >= limit) return;
    const int n0 = blockIdx.x * 128;
    const int tid = threadIdx.x;

    // staging addressing
    const int arow = tid >> 2, ak = (tid & 3) * 8;
    const int brow = tid >> 1, bk = (tid & 1) * 16;
    long aRowG = m0 + arow;
    if (rowmap) aRowG = rowmap[aRowG];
    const float* aptr = A + aRowG * lda + ak;
    const int gnw = n0 + brow;
    const bool wvalid = gnw < N;
    const unsigned short* wptr = W + (long)(wvalid ? gnw : 0) * ldw + bk;

    // fragment addressing
    const int lane = tid & 63, wv = tid >> 6;
    const int wm = wv & 1, wn = wv >> 1;
    const int fcol = lane & 15, quad = lane >> 4;
    const unsigned short* aFp = As + ((wm * 32 + fcol) * 32 + quad * 8);
    const unsigned short* bFp = Bs + ((wn * 64 + fcol) * 32 + quad * 8);

    f32x4 acc[2][4];
#pragma unroll
    for (int i = 0; i < 2; ++i)
#pragma unroll
        for (int j = 0; j < 4; ++j) acc[i][j] = (f32x4){0.f, 0.f, 0.f, 0.f};

    for (int k0 = 0; k0 < K; k0 += 32) {
        float4 x0 = *(const float4*)(aptr);
        float4 x1 = *(const float4*)(aptr + 4);
        aptr += 32;
        int4 w0 = make_int4(0, 0, 0, 0), w1 = w0;
        if (wvalid) {
            w0 = *(const int4*)(wptr);
            w1 = *(const int4*)(wptr + 8);
        }
        wptr += 32;
        short8 ap;
        ap[0] = (short)f2bf(x0.x); ap[1] = (short)f2bf(x0.y);
        ap[2] = (short)f2bf(x0.z); ap[3] = (short)f2bf(x0.w);
        ap[4] = (short)f2bf(x1.x); ap[5] = (short)f2bf(x1.y);
        ap[6] = (short)f2bf(x1.z); ap[7] = (short)f2bf(x1.w);
        __syncthreads();   // previous iteration's reads done
        *(short8*)(As + (arow * 32 + ak)) = ap;
        *(int4*)(Bs + (brow * 32 + bk)) = w0;
        *(int4*)(Bs + (brow * 32 + bk + 8)) = w1;
        __syncthreads();
        short8 a0 = *(const short8*)(aFp);
        short8 a1 = *(const short8*)(aFp + 512);
#pragma unroll
        for (int ns = 0; ns < 4; ++ns) {
            short8 bn = *(const short8*)(bFp + ns * 512);
            acc[0][ns] = __builtin_amdgcn_mfma_f32_16x16x32_bf16(a0, bn, acc[0][ns], 0, 0, 0);
            acc[1][ns] = __builtin_amdgcn_mfma_f32_16x16x32_bf16(a1, bn, acc[1][ns], 0, 0, 0);
        }
    }

    // epilogue: C/D layout col=lane&15, row=quad*4+reg
#pragma unroll
    for (int ms = 0; ms < 2; ++ms) {
        int gmb = m0 + wm * 32 + ms * 16 + quad * 4;
#pragma unroll
        for (int ns = 0; ns < 4; ++ns) {
            int gn = n0 + wn * 64 + ns * 16 + fcol;
            if (gn >= N) continue;
            int seg = (gn >= split);
            float bv = seg ? bias1[gn - split] : bias0[gn];
            int act = seg ? act1 : act0;
#pragma unroll
            for (int r = 0; r < 4; ++r) {
                int gm = gmb + r;
                if (gm >= limit) continue;
                float v = acc[ms][ns][r] + bv;
                if (act == 1) v = sigmoidf_(v);
                if (outbf) outbf[(long)gm * ld0 + gn] = f2bf(v);
                else if (!seg) out0[(long)gm * ld0 + gn] = v;
                else out1[(long)gm * ld1 + (gn - split)] = v;
            }
        }
    }
}

// ---------------------------------------------------------------------------
// Fused attention: e = relu(att_enc + att_dec) . W_att + b; softmax;
// weighted = alpha^T enc. Grid (NB, 2), 256 thr. Pruned by nt[t].
// ---------------------------------------------------------------------------
__global__ __launch_bounds__(256) void attention_kernel(
    const unsigned short* __restrict__ att_enc,   // bf16 [B*196][512]
    const float* __restrict__ adg,                // [B][2560], cols 0..511 = att_dec
    const float* __restrict__ W_att, const float* __restrict__ b_att,
    const float* __restrict__ enc, const int* __restrict__ order,
    const int* __restrict__ nt,
    float* __restrict__ weighted,                 // [B][2048]
    float* __restrict__ out_alpha, int t) {
    int b = blockIdx.x;
    if (b >= nt[t]) return;
    int half = blockIdx.y;
    int tid = threadIdx.x, lane = tid & 63, wid = tid >> 6;
    __shared__ float es[NP];
    __shared__ float al[NP];
    __shared__ float stats[2];

    // lane-private att_dec & W_att slices (d = lane*8 .. +7)
    const float* adp = adg + (long)b * 2560 + lane * 8;
    float4 ad0 = *(const float4*)(adp);
    float4 ad1 = *(const float4*)(adp + 4);
    const float* wap = W_att + lane * 8;
    float4 wa0 = *(const float4*)(wap);
    float4 wa1 = *(const float4*)(wap + 4);
    float ad[8] = {ad0.x, ad0.y, ad0.z, ad0.w, ad1.x, ad1.y, ad1.z, ad1.w};
    float wa[8] = {wa0.x, wa0.y, wa0.z, wa0.w, wa1.x, wa1.y, wa1.z, wa1.w};
    float batt = b_att[0];

    for (int p = wid; p < NP; p += 4) {
        const unsigned short* row = att_enc + ((long)b * NP + p) * 512 + lane * 8;
        int4 rv = *(const int4*)row;
        const unsigned short* us = (const unsigned short*)&rv;
        float s = 0.f;
#pragma unroll
        for (int j = 0; j < 8; ++j) {
            float v = bf2f(us[j]) + ad[j];
            v = v > 0.f ? v : 0.f;
            s += v * wa[j];
        }
#pragma unroll
        for (int o = 32; o; o >>= 1) s += __shfl_xor(s, o, 64);
        if (lane == 0) es[p] = s + batt;
    }
    __syncthreads();
    if (wid == 0) {
        float v[4], mx = -1e30f;
#pragma unroll
        for (int i = 0; i < 4; ++i) {
            int p = lane + 64 * i;
            v[i] = (p < NP) ? es[p] : -1e30f;
            mx = fmaxf(mx, v[i]);
        }
#pragma unroll
        for (int o = 32; o; o >>= 1) mx = fmaxf(mx, __shfl_xor(mx, o, 64));
        float s = 0.f;
#pragma unroll
        for (int i = 0; i < 4; ++i) {
            int p = lane + 64 * i;
            if (p < NP) s += __expf(v[i] - mx);
        }
#pragma unroll
        for (int o = 32; o; o >>= 1) s += __shfl_xor(s, o, 64);
        if (lane == 0) { stats[0] = mx; stats[1] = 1.f / s; }
    }
    __syncthreads();
    float mm = stats[0], inv = stats[1];
    if (tid < NP) {
        float a = __expf(es[tid] - mm) * inv;
        al[tid] = a;
        if (half == 0) out_alpha[((long)b * NTM + t) * NP + tid] = a;
    }
    __syncthreads();
    // weighted: this block's 1024-column half, float4 per thread
    int d = half * 1024 + tid * 4;
    const float* eb = enc + ((long)order[b] * NP) * DENC + d;
    float4 acc = make_float4(0.f, 0.f, 0.f, 0.f);
    for (int p = 0; p < NP; ++p) {
        float a = al[p];
        float4 ev = *(const float4*)(eb + (long)p * DENC);
        acc.x += a * ev.x; acc.y += a * ev.y; acc.z += a * ev.z; acc.w += a * ev.w;
    }
    *(float4*)(weighted + (long)b * DENC + d) = acc;
}

// xh = [emb_t | weighted*gate | h]; grid (12, NB)
__global__ void build_xh_kernel(const float* __restrict__ emb,
                                const int* __restrict__ caps,
                                const float* __restrict__ weighted,
                                const float* __restrict__ adg,
                                const float* __restrict__ h,
                                const int* __restrict__ nt,
                                float* __restrict__ xh, int t) {
    int b = blockIdx.y;
    if (b >= nt[t]) return;
    int col = blockIdx.x * 256 + threadIdx.x;   // < 3072
    float v;
    if (col < 512) {
        v = emb[(long)caps[b * NT + t] * 512 + col];
    } else if (col < 2560) {
        int d = col - 512;
        v = weighted[(long)b * DENC + d] * adg[(long)b * 2560 + 512 + d];
    } else {
        v = h[(long)b * DDEC + (col - 2560)];
    }
    xh[(long)b * 3072 + col] = v;
}

// LSTM pointwise: update h,c for active rows. grid (2, NB)
__global__ void lstm_kernel(const float* __restrict__ gates,
                            float* __restrict__ c,
                            float* __restrict__ h,
                            const int* __restrict__ nt, int t) {
    int b = blockIdx.y;
    if (b >= nt[t]) return;
    int d = blockIdx.x * 256 + threadIdx.x;   // < 512
    const float* g = gates + ((long)b << 11);
    float ig = sigmoidf_(g[d]);
    float fg = sigmoidf_(g[512 + d]);
    float gg = tanhf(g[1024 + d]);
    float og = sigmoidf_(g[1536 + d]);
    long idx = (long)b * DDEC + d;
    float cn = fg * c[idx] + ig * gg;
    c[idx] = cn;
    h[idx] = og * tanhf(cn);
}

// ---------------------------------------------------------------------------
extern "C" void kernel_launch(void* const* d_in, const int* in_sizes, int n_in,
                              void* d_out, int out_size, void* d_ws, size_t ws_size,
                              hipStream_t stream) {
    const float* enc_out   = (const float*)d_in[0];
    const int*   enc_caps  = (const int*)d_in[1];
    const int*   len_caps  = (const int*)d_in[2];
    const float* emb       = (const float*)d_in[3];
    const float* W_enc_att = (const float*)d_in[4];
    const float* b_enc_att = (const float*)d_in[5];
    const float* W_dec_att = (const float*)d_in[6];
    const float* b_dec_att = (const float*)d_in[7];
    const float* W_att     = (const float*)d_in[8];
    const float* b_att     = (const float*)d_in[9];
    const float* W_init_h  = (const float*)d_in[10];
    const float* b_init_h  = (const float*)d_in[11];
    const float* W_init_c  = (const float*)d_in[12];
    const float* b_init_c  = (const float*)d_in[13];
    const float* W_ih      = (const float*)d_in[14];
    const float* b_ih      = (const float*)d_in[15];
    const float* W_hh      = (const float*)d_in[16];
    const float* b_hh      = (const float*)d_in[17];
    const float* W_fbeta   = (const float*)d_in[18];
    const float* b_fbeta   = (const float*)d_in[19];
    const float* W_fc      = (const float*)d_in[20];
    const float* b_fc      = (const float*)d_in[21];

    float* out        = (float*)d_out;
    float* out_caps   = out;
    float* out_lendec = out + 3840;
    float* out_pred   = out + 3968;
    float* out_alpha  = out + 3968 + 37120000;
    float* out_order  = out + 3968 + 37120000 + 727552;

    char*  wsb = (char*)d_ws;
    size_t off = 0;
    auto alloc = [&](size_t bytes) -> void* {
        void* p = wsb + off;
        off += (bytes + 255) & ~(size_t)255;
        return p;
    };
    int*   order_ws = (int*)alloc(NB * 4);
    int*   nt_ws    = (int*)alloc(NTM * 4);
    int*   caps_ws  = (int*)alloc(NB * NT * 4);
    int*   rowmap   = (int*)alloc((size_t)NB * NP * 4);
    float* mu       = (float*)alloc((size_t)NB * DENC * 4);
    float* h        = (float*)alloc((size_t)NB * DDEC * 4);
    float* c        = (float*)alloc((size_t)NB * DDEC * 4);
    float* adg      = (float*)alloc((size_t)NB * 2560 * 4);
    float* weighted = (float*)alloc((size_t)NB * DENC * 4);
    float* xh       = (float*)alloc((size_t)NB * 3072 * 4);
    float* gates    = (float*)alloc((size_t)NB * 4 * DDEC * 4);
    unsigned short* att_enc_bf = (unsigned short*)alloc((size_t)NB * NP * 512 * 2);
    unsigned short* Wq_enc  = (unsigned short*)alloc((size_t)512 * 2048 * 2);
    unsigned short* Wq_init = (unsigned short*)alloc((size_t)1024 * 2048 * 2);
    unsigned short* Wq_adg  = (unsigned short*)alloc((size_t)2560 * 512 * 2);
    unsigned short* Wq_ihh  = (unsigned short*)alloc((size_t)2048 * 3072 * 2);
    unsigned short* Wq_fc   = (unsigned short*)alloc((size_t)NV * 512 * 2);
    float* bihh = (float*)alloc(2048 * 4);

    // ---- prologue ----
    sort_kernel<<<1, NB, 0, stream>>>(len_caps, enc_caps, out_caps, out_lendec,
                                      out_order, order_ws, nt_ws, caps_ws);
    fill_zero4<<<36960, 256, 0, stream>>>((float4*)out_pred, 9461888);  // preds+alphas
    rowmap_kernel<<<98, 256, 0, stream>>>(order_ws, rowmap);
    mu_kernel<<<dim3(NB, DENC / 256), 256, 0, stream>>>(enc_out, order_ws, mu);

    conv_bf<<<(512 * 2048) / 256, 256, 0, stream>>>(W_enc_att, Wq_enc, 512 * 2048);
    conv_bf<<<(512 * 2048) / 256, 256, 0, stream>>>(W_init_h, Wq_init, 512 * 2048);
    conv_bf<<<(512 * 2048) / 256, 256, 0, stream>>>(W_init_c, Wq_init + (size_t)512 * 2048, 512 * 2048);
    conv_bf<<<(512 * 512) / 256, 256, 0, stream>>>(W_dec_att, Wq_adg, 512 * 512);
    conv_bf<<<(2048 * 512) / 256, 256, 0, stream>>>(W_fbeta, Wq_adg + (size_t)512 * 512, 2048 * 512);
    kconcat_ihh<<<dim3(12, 2048), 256, 0, stream>>>(W_ih, W_hh, Wq_ihh);
    conv_bf<<<(NV * 512) / 256, 256, 0, stream>>>(W_fc, Wq_fc, NV * 512);
    bias_add2<<<8, 256, 0, stream>>>(b_ih, b_hh, bihh, 2048);

    // h|c init: A=mu, W=Wq_init [1024][2048], split at 512
    gemm_mfma<<<dim3(8, 2), 256, 0, stream>>>(
        mu, DENC, nullptr, Wq_init, DENC,
        b_init_h, b_init_c, 512,
        h, DDEC, c, DDEC, nullptr, 0, 0,
        NB, 1024, DENC, nullptr, 0);

    // att_enc (bf16 out): A=enc via rowmap, W=Wq_enc [512][2048]
    gemm_mfma<<<dim3(4, 392), 256, 0, stream>>>(
        enc_out, DENC, rowmap, Wq_enc, DENC,
        b_enc_att, nullptr, 512,
        nullptr, 512, nullptr, 0, att_enc_bf, 0, 0,
        NB * NP, 512, DENC, nullptr, 0);

    // ---- time loop ----
    for (int t = 0; t < NTM; ++t) {
        // adg = [att_dec | sigmoid(gate)]: A=h, W=Wq_adg [2560][512]
        gemm_mfma<<<dim3(20, 2), 256, 0, stream>>>(
            h, DDEC, nullptr, Wq_adg, DDEC,
            b_dec_att, b_fbeta, 512,
            adg, 2560, adg + 512, 2560, nullptr, 0, 1,
            NB, 2560, DDEC, nt_ws, t);
        // fused attention
        attention_kernel<<<dim3(NB, 2), 256, 0, stream>>>(
            att_enc_bf, adg, W_att, b_att, enc_out, order_ws, nt_ws,
            weighted, out_alpha, t);
        // xh = [emb | weighted*gate | h]
        build_xh_kernel<<<dim3(12, NB), 256, 0, stream>>>(
            emb, caps_ws, weighted, adg, h, nt_ws, xh, t);
        // gates = xh @ Wq_ihh^T + bihh
        gemm_mfma<<<dim3(16, 2), 256, 0, stream>>>(
            xh, 3072, nullptr, Wq_ihh, 3072,
            bihh, nullptr, 2048,
            gates, 2048, nullptr, 0, nullptr, 0, 0,
            NB, 2048, 3072, nt_ws, t);
        // LSTM pointwise
        lstm_kernel<<<dim3(2, NB), 256, 0, stream>>>(gates, c, h, nt_ws, t);
        // preds = h @ Wq_fc^T (active rows only; rest pre-zeroed)
        gemm_mfma<<<dim3(79, 2), 256, 0, stream>>>(
            h, DDEC, nullptr, Wq_fc, DDEC,
            b_fc, nullptr, NV,
            out_pred + (long)t * NV, (long)NTM * NV, nullptr, 0, nullptr, 0, 0,
            NB, NV, DDEC, nt_ws, t);
    }
}